// Round 1
// baseline (1355.529 us; speedup 1.0000x reference)
//
#include <hip/hip_runtime.h>
#include <cstdint>
#include <cstddef>

#define WAVES_PER_BLOCK 4

// Mark segment start offsets from sorted seg_ids.
// seg_start[n] = first index i with seg_ids[i] >= n; seg_start[N] = M.
__global__ __launch_bounds__(256) void seg_bounds_kernel(
    const int* __restrict__ seg_ids, int* __restrict__ seg_start, int M, int N) {
    int i = blockIdx.x * blockDim.x + threadIdx.x;
    if (i >= M) return;
    int cur  = seg_ids[i];
    int prev = (i == 0) ? -1 : seg_ids[i - 1];
    for (int n = prev + 1; n <= cur; ++n) seg_start[n] = i;
    if (i == M - 1) {
        for (int n = cur + 1; n <= N; ++n) seg_start[n] = M;
    }
}

// One wave per segment: online-softmax weighted aggregation in a single pass
// over the segment's contiguous message rows. 64 lanes x float2 = 128 dims.
__global__ __launch_bounds__(256) void seg_softmax_agg_kernel(
    const float2* __restrict__ msgs2,      // [M][64] float2 view of [M,128] f32
    const int*    __restrict__ timestamps, // [M]
    const float2* __restrict__ W2,         // [64] float2 view of [128]
    const float*  __restrict__ b_ptr,      // scalar
    const int*    __restrict__ seg_start,  // [N+1]
    float2*       __restrict__ out_agg2,   // [N][64]
    float*        __restrict__ out_ts,     // [N] (timestamps as f32, exact < 2^24)
    int N) {
    const int wave = threadIdx.x >> 6;
    const int lane = threadIdx.x & 63;
    const int n = blockIdx.x * WAVES_PER_BLOCK + wave;
    if (n >= N) return;

    const int s = seg_start[n];
    const int e = seg_start[n + 1];

    const float2 w2 = W2[lane];
    const float  bb = b_ptr[0];

    float2 acc  = make_float2(0.0f, 0.0f);
    float  mrun = -INFINITY;   // running max
    float  denom = 0.0f;       // running sum exp(score - mrun)
    int    tsm  = (-2147483647 - 1);

    if (e > s) {
        // software pipeline: prefetch next row while reducing current
        float2 mv = msgs2[(size_t)s * 64 + lane];
        int    tv = timestamps[s];
        for (int j = s; j < e; ++j) {
            float2 mv_cur = mv;
            int    tv_cur = tv;
            if (j + 1 < e) {
                mv = msgs2[(size_t)(j + 1) * 64 + lane];
                tv = timestamps[j + 1];
            }
            // per-row score: dot(msg, W) + b, full-wave reduce
            float part = mv_cur.x * w2.x + mv_cur.y * w2.y;
            #pragma unroll
            for (int off = 32; off >= 1; off >>= 1)
                part += __shfl_xor(part, off);
            const float sc = part + bb;   // wave-uniform now

            // online softmax update
            const float mnew  = fmaxf(mrun, sc);
            const float alpha = __expf(mrun - mnew);  // first iter: exp(-inf)=0
            const float wgt   = __expf(sc - mnew);
            denom = denom * alpha + wgt;
            acc.x = acc.x * alpha + wgt * mv_cur.x;
            acc.y = acc.y * alpha + wgt * mv_cur.y;
            tsm   = (tv_cur > tsm) ? tv_cur : tsm;
            mrun  = mnew;
        }
    }

    const float inv = (e > s) ? (1.0f / denom) : 0.0f;
    float2 o;
    o.x = acc.x * inv;
    o.y = acc.y * inv;
    out_agg2[(size_t)n * 64 + lane] = o;
    if (lane == 0) {
        // segment_max identity for empty int32 segments = INT32_MIN
        out_ts[n] = (e > s) ? (float)tsm : -2147483648.0f;
    }
}

extern "C" void kernel_launch(void* const* d_in, const int* in_sizes, int n_in,
                              void* d_out, int out_size, void* d_ws, size_t ws_size,
                              hipStream_t stream) {
    const float* msgs       = (const float*)d_in[0];
    const int*   seg_ids    = (const int*)d_in[1];
    const int*   timestamps = (const int*)d_in[2];
    const float* W          = (const float*)d_in[3];
    const float* b          = (const float*)d_in[4];

    const int M = in_sizes[1];          // 2,000,000
    const int N = out_size / 129;       // out = N*128 agg + N ts  (D=128)

    int* seg_start = (int*)d_ws;        // (N+1) ints

    float* out_agg = (float*)d_out;
    float* out_ts  = (float*)d_out + (size_t)N * 128;

    seg_bounds_kernel<<<(M + 255) / 256, 256, 0, stream>>>(seg_ids, seg_start, M, N);

    const int blocks = (N + WAVES_PER_BLOCK - 1) / WAVES_PER_BLOCK;
    seg_softmax_agg_kernel<<<blocks, 256, 0, stream>>>(
        (const float2*)msgs, timestamps, (const float2*)W, b, seg_start,
        (float2*)out_agg, out_ts, N);
}